// Round 10
// baseline (268.732 us; speedup 1.0000x reference)
//
#include <hip/hip_runtime.h>
#include <hip/hip_fp16.h>
#include <cfloat>

// NearestNeighborGraph: S=16, N=2048, D=64, K=16.
// Round-10: MFMA scan + ORDER-STATISTIC threshold + exact fp32 rescue.
//  Pass 1: f16 MFMA over all pairs; per (row, wave, C-col) group (128 groups
//          x 16 j per row) track the group MIN in registers (v_min only --
//          no scoreboard, no push/drain).
//  Thr:    M = 16th-smallest of the 128 group minima (valid upper bound on
//          the approx 16th: the 16 best groups give 16 distinct j <= M).
//          tau = M + 1.0 (f16 error 2*eps ~ 0.2 -> 5x margin) provably keeps
//          every exact top-16 member.
//  Pass 2: MFMA re-scan, filter vs tau, push survivors (~20/row, cap 96)
//          into per-row LDS rings.
//  Rescue: exact fp32 recompute (bit-identical round-1 fmaf chains) + lex
//          (d2,j) top-16 == reference tie-break -> output identical to r1-9.
//  8 waves/block, 43.5 KB LDS (minb/md/mi/ring time-aliased) -> 16 waves/CU.

typedef _Float16 half8 __attribute__((ext_vector_type(8)));
typedef float    f32x4 __attribute__((ext_vector_type(4)));

constexpr int NS = 16, NP = 2048, ND = 64, KK = 16;
constexpr int NW  = 8;              // waves per block
constexpr int NT  = NW * 64;        // 512 threads
constexpr int JW  = NP / NW;        // 256 j per wave
constexpr int NJT = JW / 16;        // 16 j-tiles per wave per pass
constexpr int MS  = 17;             // merge-tree stride
constexpr int RCAP = 96;            // candidate ring slots per row
constexpr float MARGIN = 1.0f;

// ---- prep: x2 (rotated chain, exact round-1 j-side value) + f16 copy ----
__global__ void prep_kernel(const float* __restrict__ h, float* __restrict__ x2,
                            _Float16* __restrict__ hh)
{
    int g = blockIdx.x * 256 + threadIdx.x;          // global row 0..NS*NP-1
    const float4* row = (const float4*)(h + (size_t)g * ND);
    int ph = g & 15;
    float a0 = 0.f, a1 = 0.f, a2 = 0.f, a3 = 0.f;
    #pragma unroll
    for (int k = 0; k < 16; ++k) {
        float4 v = row[(k + ph) & 15];
        a0 = fmaf(v.x, v.x, a0); a1 = fmaf(v.y, v.y, a1);
        a2 = fmaf(v.z, v.z, a2); a3 = fmaf(v.w, v.w, a3);
    }
    x2[g] = (a0 + a1) + (a2 + a3);
    _Float16* dst = hh + (size_t)g * ND;
    #pragma unroll
    for (int k = 0; k < 8; ++k) {
        float4 v0 = row[2 * k], v1 = row[2 * k + 1];
        half8 p;
        p[0] = (_Float16)v0.x; p[1] = (_Float16)v0.y;
        p[2] = (_Float16)v0.z; p[3] = (_Float16)v0.w;
        p[4] = (_Float16)v1.x; p[5] = (_Float16)v1.y;
        p[6] = (_Float16)v1.z; p[7] = (_Float16)v1.w;
        *(half8*)(dst + k * 8) = p;
    }
}

// plain value insert (threshold path: only the 16th VALUE matters)
__device__ __forceinline__ void insert16(float (&d)[KK], int (&ix)[KK],
                                         float v, int j)
{
    #pragma unroll
    for (int p = KK - 1; p > 0; --p) {
        bool sh = v < d[p - 1];
        bool he = v < d[p];
        float nd = sh ? d[p - 1] : (he ? v : d[p]);
        int   ni = sh ? ix[p - 1] : (he ? j : ix[p]);
        d[p] = nd; ix[p] = ni;
    }
    if (v < d[0]) { d[0] = v; ix[0] = j; }
}

// lexicographic (d2, j) insert == top_k tie-break (lowest index on equal d2)
__device__ __forceinline__ bool lexlt(float a, int ja, float b, int jb)
{
    return (a < b) || (a == b && ja < jb);
}
__device__ __forceinline__ void insert16x(float (&d)[KK], int (&ix)[KK],
                                          float v, int j)
{
    #pragma unroll
    for (int p = KK - 1; p > 0; --p) {
        bool sh = lexlt(v, j, d[p - 1], ix[p - 1]);
        bool he = lexlt(v, j, d[p], ix[p]);
        float nd = sh ? d[p - 1] : (he ? v : d[p]);
        int   ni = sh ? ix[p - 1] : (he ? j : ix[p]);
        d[p] = nd; ix[p] = ni;
    }
    if (lexlt(v, j, d[0], ix[0])) { d[0] = v; ix[0] = j; }
}

__global__ __launch_bounds__(NT)
void knn_mfma(const float* __restrict__ h, const _Float16* __restrict__ hh,
              const float* __restrict__ x2g, float* __restrict__ out)
{
    // 10880 floats = 43520 B -> 2 blocks/CU (grid-limited), 16 waves/CU.
    // X region time-aliased: minb (pass1/thr-read) -> md/mi (thr merge) ->
    // ring (pass2/rescue) -> md/mi (final merge); all barrier-separated.
    __shared__ __align__(16) float smem[10880];
    float* ldsx2  = smem;                    // [0,2048)
    float* ldsthr = smem + 2048;             // [2048,2112)
    int*   rcnt   = (int*)(smem + 2112);     // [2112,2176)
    float* X      = smem + 2176;             // [2176,10880) = 8704 floats
    float* minb   = X;                       // 8 waves x 64 rows x 17
    float* md     = X;                       // 4 regions x 64 x 17
    int*   mi     = (int*)(X + 4352);
    int*   ring   = (int*)X;                 // 64 rows x 97

    const int t   = threadIdx.x;
    const int ln  = t & 63;
    const int qd  = ln >> 4;                 // quad within wave
    const int cl  = ln & 15;                 // col within quad group
    const int q   = t >> 6;                  // wave id (j-eighth)
    const int s   = blockIdx.x >> 5;
    const int rb  = blockIdx.x & 31;
    const int rowbase = rb * 64;
    const float*    __restrict__ hs  = h  + (size_t)s * NP * ND;
    const _Float16* __restrict__ hhs = hh + (size_t)s * NP * ND;

    ((float4*)ldsx2)[t] = ((const float4*)(x2g + s * NP))[t];  // 512*4 = 2048
    if (t < 64) rcnt[t] = 0;

    // A-frags: 4 i-tiles x 2 K-chunks; lane holds A[m=cl][k=qd*8..+7]
    half8 afr[4][2];
    #pragma unroll
    for (int it = 0; it < 4; ++it) {
        const _Float16* ap = hhs + (size_t)(rowbase + it * 16 + cl) * ND + qd * 8;
        afr[it][0] = *(const half8*)(ap);
        afr[it][1] = *(const half8*)(ap + 32);
    }
    __syncthreads();

    // x2 (approx side) for lane's 16 C-layout rows (row = it*16 + qd*4 + r)
    float x2r[16];
    #pragma unroll
    for (int it = 0; it < 4; ++it)
        #pragma unroll
        for (int r = 0; r < 4; ++r)
            x2r[it * 4 + r] = ldsx2[rowbase + it * 16 + qd * 4 + r];

    const int jbase = q * JW;

    // ================= pass 1: MFMA scan, group minima only ==============
    float rmin[16];
    #pragma unroll
    for (int k = 0; k < 16; ++k) rmin[k] = FLT_MAX;

    {
        const _Float16* bp0 = hhs + (size_t)(jbase + cl) * ND + qd * 8;
        half8 nlo = *(const half8*)(bp0);
        half8 nhi = *(const half8*)(bp0 + 32);
        for (int jt = 0; jt < NJT; ++jt) {
            const int j0 = jbase + jt * 16;
            half8 blo = nlo, bhi = nhi;
            const int njt = (jt + 1 < NJT) ? jt + 1 : NJT - 1;
            const _Float16* bp = hhs + (size_t)(jbase + njt * 16 + cl) * ND + qd * 8;
            nlo = *(const half8*)(bp);
            nhi = *(const half8*)(bp + 32);
            const float x2j = ldsx2[j0 + cl];

            f32x4 acc[4];
            #pragma unroll
            for (int it = 0; it < 4; ++it) {
                acc[it] = __builtin_amdgcn_mfma_f32_16x16x32_f16(
                              afr[it][0], blo, (f32x4){0.f, 0.f, 0.f, 0.f}, 0, 0, 0);
                acc[it] = __builtin_amdgcn_mfma_f32_16x16x32_f16(
                              afr[it][1], bhi, acc[it], 0, 0, 0);
            }
            #pragma unroll
            for (int it = 0; it < 4; ++it)
                #pragma unroll
                for (int r = 0; r < 4; ++r)
                    rmin[it * 4 + r] = fminf(rmin[it * 4 + r],
                        fmaf(-2.f, acc[it][r], x2r[it * 4 + r] + x2j));
        }
    }
    // publish group minima: minb[wave q][row][col cl]
    #pragma unroll
    for (int it = 0; it < 4; ++it)
        #pragma unroll
        for (int r = 0; r < 4; ++r)
            minb[q * 1088 + (it * 16 + qd * 4 + r) * MS + cl] = rmin[it * 4 + r];
    __syncthreads();

    // ====== threshold: 16th-smallest of 128 group minima per row =========
    float dist[KK]; int idx[KK];
    #pragma unroll
    for (int k = 0; k < KK; ++k) { dist[k] = FLT_MAX; idx[k] = 0; }
    #pragma unroll 1
    for (int c = 0; c < 16; ++c)
        insert16(dist, idx, minb[q * 1088 + ln * MS + c], 0);
    __syncthreads();             // minb reads done; X reusable as md

    #pragma unroll 1
    for (int lvl = 0; lvl < 3; ++lvl) {       // 3-level value-only merge
        const int step = 1 << lvl;
        const int m    = (step << 1) - 1;
        const bool pub = (q & m) == step;
        const bool con = (q & m) == 0;
        const int reg  = q >> (lvl + 1);
        if (pub) {
            #pragma unroll
            for (int k = 0; k < KK; ++k)
                md[(reg * 64 + ln) * MS + k] = dist[k];
        }
        __syncthreads();
        if (con) {
            #pragma unroll 1
            for (int k = 0; k < KK; ++k)
                insert16(dist, idx, md[(reg * 64 + ln) * MS + k], 0);
        }
        __syncthreads();
    }
    if (q == 0) ldsthr[ln] = dist[KK - 1] + MARGIN;   // tau = M + margin
    __syncthreads();

    float thrv[16];
    #pragma unroll
    for (int it = 0; it < 4; ++it)
        #pragma unroll
        for (int r = 0; r < 4; ++r)
            thrv[it * 4 + r] = ldsthr[it * 16 + qd * 4 + r];

    // ================= pass 2: re-scan, fill candidate rings ==============
    {
        const _Float16* bp0 = hhs + (size_t)(jbase + cl) * ND + qd * 8;
        half8 nlo = *(const half8*)(bp0);
        half8 nhi = *(const half8*)(bp0 + 32);
        for (int jt = 0; jt < NJT; ++jt) {
            const int j0 = jbase + jt * 16;
            half8 blo = nlo, bhi = nhi;
            const int njt = (jt + 1 < NJT) ? jt + 1 : NJT - 1;
            const _Float16* bp = hhs + (size_t)(jbase + njt * 16 + cl) * ND + qd * 8;
            nlo = *(const half8*)(bp);
            nhi = *(const half8*)(bp + 32);
            const float x2j = ldsx2[j0 + cl];

            f32x4 acc[4];
            #pragma unroll
            for (int it = 0; it < 4; ++it) {
                acc[it] = __builtin_amdgcn_mfma_f32_16x16x32_f16(
                              afr[it][0], blo, (f32x4){0.f, 0.f, 0.f, 0.f}, 0, 0, 0);
                acc[it] = __builtin_amdgcn_mfma_f32_16x16x32_f16(
                              afr[it][1], bhi, acc[it], 0, 0, 0);
            }
            #pragma unroll
            for (int it = 0; it < 4; ++it) {
                #pragma unroll
                for (int r = 0; r < 4; ++r) {
                    float d2 = fmaf(-2.f, acc[it][r], x2r[it * 4 + r] + x2j);
                    if (d2 < thrv[it * 4 + r]) {
                        int rw = it * 16 + qd * 4 + r;
                        int slot = atomicAdd(&rcnt[rw], 1);
                        if (slot < RCAP) ring[rw * 97 + slot] = j0 + cl;
                    }
                }
            }
        }
    }
    __syncthreads();

    // ========== rescue: exact fp32 recompute of candidates ===============
    const int myrow = rowbase + ln;
    float4 A[16];
    {
        const float4* ra = (const float4*)(hs + (size_t)myrow * ND);
        #pragma unroll
        for (int k = 0; k < 16; ++k) A[k] = ra[k];
    }
    float x2i;   // ascending chain (exact round-1 i-side value)
    {
        float a0 = 0.f, a1 = 0.f, a2 = 0.f, a3 = 0.f;
        #pragma unroll
        for (int k = 0; k < 16; ++k) {
            a0 = fmaf(A[k].x, A[k].x, a0); a1 = fmaf(A[k].y, A[k].y, a1);
            a2 = fmaf(A[k].z, A[k].z, a2); a3 = fmaf(A[k].w, A[k].w, a3);
        }
        x2i = (a0 + a1) + (a2 + a3);
    }
    #pragma unroll
    for (int k = 0; k < KK; ++k) { dist[k] = FLT_MAX; idx[k] = 0; }

    const int cntR = min(rcnt[ln], RCAP);
    #pragma unroll 1
    for (int k = q; k < cntR; k += NW) {
        int j = ring[ln * 97 + k];
        const float4* cv = (const float4*)(hs + (size_t)j * ND);
        float a0 = 0.f, a1 = 0.f, a2 = 0.f, a3 = 0.f;
        #pragma unroll
        for (int kk = 0; kk < 16; ++kk) {
            float4 c = cv[kk];
            a0 = fmaf(A[kk].x, c.x, a0); a1 = fmaf(A[kk].y, c.y, a1);
            a2 = fmaf(A[kk].z, c.z, a2); a3 = fmaf(A[kk].w, c.w, a3);
        }
        float dotv = (a0 + a1) + (a2 + a3);
        float d2 = fmaf(-2.0f, dotv, x2i + ldsx2[j]);
        insert16x(dist, idx, d2, j);
    }
    __syncthreads();             // ring reads done; X reusable as md/mi

    // ---- final exact merge (lex) across the 8 waves ----
    #pragma unroll 1
    for (int lvl = 0; lvl < 3; ++lvl) {
        const int step = 1 << lvl;
        const int m    = (step << 1) - 1;
        const bool pub = (q & m) == step;
        const bool con = (q & m) == 0;
        const int reg  = q >> (lvl + 1);
        if (pub) {
            #pragma unroll
            for (int k = 0; k < KK; ++k) {
                md[(reg * 64 + ln) * MS + k] = dist[k];
                mi[(reg * 64 + ln) * MS + k] = idx[k];
            }
        }
        __syncthreads();
        if (con) {
            #pragma unroll 1
            for (int k = 0; k < KK; ++k)
                insert16x(dist, idx, md[(reg * 64 + ln) * MS + k],
                                     mi[(reg * 64 + ln) * MS + k]);
        }
        __syncthreads();
    }

    // ---- output (wave 0) ----
    if (q == 0) {
        const int off = s * NP;
        const size_t rg = (size_t)off + myrow;
        float* o0 = out + rg * KK;
        float* o1 = out + (size_t)NS * NP * KK + rg * KK;
        float* o2 = out + (size_t)2 * NS * NP * KK + rg * KK;
        #pragma unroll
        for (int k = 0; k < KK; ++k) o0[k] = dist[k];
        #pragma unroll
        for (int k = 0; k < KK; ++k) o1[k] = (float)(idx[k] + off);
        #pragma unroll
        for (int k = 0; k < KK; ++k) o2[k] = (float)(off + myrow);
    }
}

extern "C" void kernel_launch(void* const* d_in, const int* in_sizes, int n_in,
                              void* d_out, int out_size, void* d_ws, size_t ws_size,
                              hipStream_t stream)
{
    const float* h = (const float*)d_in[0];
    float* out = (float*)d_out;
    float*    x2 = (float*)d_ws;                     // 32768 floats (128 KB)
    _Float16* hh = (_Float16*)(x2 + NS * NP);        // 16*2048*64 halves (4 MB)

    hipLaunchKernelGGL(prep_kernel, dim3(NS * NP / 256), dim3(256), 0, stream,
                       h, x2, hh);
    hipLaunchKernelGGL(knn_mfma, dim3(NS * 32), dim3(NT), 0, stream,
                       h, hh, x2, out);
}

// Round 11
// 268.669 us; speedup vs baseline: 1.0002x; 1.0002x over previous
//
#include <hip/hip_runtime.h>
#include <hip/hip_fp16.h>
#include <cfloat>

// NearestNeighborGraph: S=16, N=2048, D=64, K=16.
// Round-11 = round-10 algorithm (MFMA scan + order-statistic threshold +
// exact fp32 rescue) with the latency fixed:
//  - 4-deep software-pipelined B-fragment feed in both MFMA passes (fully
//    unrolled, static buffer indices) -> prefetch distance ~500 cyc covers
//    L2/L3 latency (round 9/10 had 1-tile = ~120 cyc -> per-tile vmcnt stall
//    dominated: 160 of 211 us was stall).
//  - rescue processes 2 candidates with overlapped gathers (ILP).
//  - prep kernel re-gridded to 512 blocks x 64 threads (was 128x256 ->
//    half the CUs idle).
// Numerics bit-identical to rounds 1-10 (same chains, same tau bound).

typedef _Float16 half8 __attribute__((ext_vector_type(8)));
typedef float    f32x4 __attribute__((ext_vector_type(4)));

constexpr int NS = 16, NP = 2048, ND = 64, KK = 16;
constexpr int NW  = 8;              // waves per block
constexpr int NT  = NW * 64;        // 512 threads
constexpr int JW  = NP / NW;        // 256 j per wave
constexpr int NJT = JW / 16;        // 16 j-tiles per wave per pass
constexpr int MS  = 17;             // merge-tree stride
constexpr int RCAP = 96;            // candidate ring slots per row
constexpr float MARGIN = 1.0f;

// ---- prep: x2 (rotated chain, exact round-1 j-side value) + f16 copy ----
__global__ __launch_bounds__(64)
void prep_kernel(const float* __restrict__ h, float* __restrict__ x2,
                 _Float16* __restrict__ hh)
{
    int g = blockIdx.x * 64 + threadIdx.x;           // global row 0..NS*NP-1
    const float4* row = (const float4*)(h + (size_t)g * ND);
    int ph = g & 15;
    float a0 = 0.f, a1 = 0.f, a2 = 0.f, a3 = 0.f;
    #pragma unroll
    for (int k = 0; k < 16; ++k) {
        float4 v = row[(k + ph) & 15];
        a0 = fmaf(v.x, v.x, a0); a1 = fmaf(v.y, v.y, a1);
        a2 = fmaf(v.z, v.z, a2); a3 = fmaf(v.w, v.w, a3);
    }
    x2[g] = (a0 + a1) + (a2 + a3);
    _Float16* dst = hh + (size_t)g * ND;
    #pragma unroll
    for (int k = 0; k < 8; ++k) {
        float4 v0 = row[2 * k], v1 = row[2 * k + 1];
        half8 p;
        p[0] = (_Float16)v0.x; p[1] = (_Float16)v0.y;
        p[2] = (_Float16)v0.z; p[3] = (_Float16)v0.w;
        p[4] = (_Float16)v1.x; p[5] = (_Float16)v1.y;
        p[6] = (_Float16)v1.z; p[7] = (_Float16)v1.w;
        *(half8*)(dst + k * 8) = p;
    }
}

// plain value insert (threshold path: only the 16th VALUE matters)
__device__ __forceinline__ void insert16(float (&d)[KK], int (&ix)[KK],
                                         float v, int j)
{
    #pragma unroll
    for (int p = KK - 1; p > 0; --p) {
        bool sh = v < d[p - 1];
        bool he = v < d[p];
        float nd = sh ? d[p - 1] : (he ? v : d[p]);
        int   ni = sh ? ix[p - 1] : (he ? j : ix[p]);
        d[p] = nd; ix[p] = ni;
    }
    if (v < d[0]) { d[0] = v; ix[0] = j; }
}

// lexicographic (d2, j) insert == top_k tie-break (lowest index on equal d2)
__device__ __forceinline__ bool lexlt(float a, int ja, float b, int jb)
{
    return (a < b) || (a == b && ja < jb);
}
__device__ __forceinline__ void insert16x(float (&d)[KK], int (&ix)[KK],
                                          float v, int j)
{
    #pragma unroll
    for (int p = KK - 1; p > 0; --p) {
        bool sh = lexlt(v, j, d[p - 1], ix[p - 1]);
        bool he = lexlt(v, j, d[p], ix[p]);
        float nd = sh ? d[p - 1] : (he ? v : d[p]);
        int   ni = sh ? ix[p - 1] : (he ? j : ix[p]);
        d[p] = nd; ix[p] = ni;
    }
    if (lexlt(v, j, d[0], ix[0])) { d[0] = v; ix[0] = j; }
}

// exact fp32 dot chain (bit-identical round-1 order)
__device__ __forceinline__ float dot64(const float4 (&A)[16],
                                       const float4* __restrict__ cv)
{
    float a0 = 0.f, a1 = 0.f, a2 = 0.f, a3 = 0.f;
    #pragma unroll
    for (int kk = 0; kk < 16; ++kk) {
        float4 c = cv[kk];
        a0 = fmaf(A[kk].x, c.x, a0); a1 = fmaf(A[kk].y, c.y, a1);
        a2 = fmaf(A[kk].z, c.z, a2); a3 = fmaf(A[kk].w, c.w, a3);
    }
    return (a0 + a1) + (a2 + a3);
}

__global__ __launch_bounds__(NT)
void knn_mfma(const float* __restrict__ h, const _Float16* __restrict__ hh,
              const float* __restrict__ x2g, float* __restrict__ out)
{
    // 10880 floats = 43520 B. X region time-aliased (barrier-separated):
    // minb -> md/mi (thr merge) -> ring -> md/mi (final merge).
    __shared__ __align__(16) float smem[10880];
    float* ldsx2  = smem;                    // [0,2048)
    float* ldsthr = smem + 2048;             // [2048,2112)
    int*   rcnt   = (int*)(smem + 2112);     // [2112,2176)
    float* X      = smem + 2176;             // [2176,10880) = 8704 floats
    float* minb   = X;                       // 8 waves x 64 rows x 17
    float* md     = X;                       // 4 regions x 64 x 17
    int*   mi     = (int*)(X + 4352);
    int*   ring   = (int*)X;                 // 64 rows x 97

    const int t   = threadIdx.x;
    const int ln  = t & 63;
    const int qd  = ln >> 4;                 // quad within wave
    const int cl  = ln & 15;                 // col within quad group
    const int q   = t >> 6;                  // wave id (j-eighth)
    const int s   = blockIdx.x >> 5;
    const int rb  = blockIdx.x & 31;
    const int rowbase = rb * 64;
    const float*    __restrict__ hs  = h  + (size_t)s * NP * ND;
    const _Float16* __restrict__ hhs = hh + (size_t)s * NP * ND;

    ((float4*)ldsx2)[t] = ((const float4*)(x2g + s * NP))[t];  // 512*4 = 2048
    if (t < 64) rcnt[t] = 0;

    // A-frags: 4 i-tiles x 2 K-chunks; lane holds A[m=cl][k=qd*8..+7]
    half8 afr[4][2];
    #pragma unroll
    for (int it = 0; it < 4; ++it) {
        const _Float16* ap = hhs + (size_t)(rowbase + it * 16 + cl) * ND + qd * 8;
        afr[it][0] = *(const half8*)(ap);
        afr[it][1] = *(const half8*)(ap + 32);
    }
    __syncthreads();

    // x2 (approx side) for lane's 16 C-layout rows (row = it*16 + qd*4 + r)
    float x2r[16];
    #pragma unroll
    for (int it = 0; it < 4; ++it)
        #pragma unroll
        for (int r = 0; r < 4; ++r)
            x2r[it * 4 + r] = ldsx2[rowbase + it * 16 + qd * 4 + r];

    const int jbase = q * JW;
    const _Float16* __restrict__ bbase = hhs + (size_t)(jbase + cl) * ND + qd * 8;

    // ================= pass 1: MFMA scan, group minima only ==============
    float rmin[16];
    #pragma unroll
    for (int k = 0; k < 16; ++k) rmin[k] = FLT_MAX;

    {
        half8 plo[4], phi[4];
        #pragma unroll
        for (int p = 0; p < 4; ++p) {
            const _Float16* bp = bbase + (size_t)(p * 16) * ND;
            plo[p] = *(const half8*)(bp);
            phi[p] = *(const half8*)(bp + 32);
        }
        #pragma unroll
        for (int jt = 0; jt < NJT; ++jt) {
            const int j0 = jbase + jt * 16;
            half8 blo = plo[jt & 3], bhi = phi[jt & 3];
            {   // prefetch tile jt+4 (clamped)
                const int nt = (jt + 4 < NJT) ? jt + 4 : NJT - 1;
                const _Float16* bp = bbase + (size_t)(nt * 16) * ND;
                plo[jt & 3] = *(const half8*)(bp);
                phi[jt & 3] = *(const half8*)(bp + 32);
            }
            const float x2j = ldsx2[j0 + cl];

            f32x4 acc[4];
            #pragma unroll
            for (int it = 0; it < 4; ++it) {
                acc[it] = __builtin_amdgcn_mfma_f32_16x16x32_f16(
                              afr[it][0], blo, (f32x4){0.f, 0.f, 0.f, 0.f}, 0, 0, 0);
                acc[it] = __builtin_amdgcn_mfma_f32_16x16x32_f16(
                              afr[it][1], bhi, acc[it], 0, 0, 0);
            }
            #pragma unroll
            for (int it = 0; it < 4; ++it)
                #pragma unroll
                for (int r = 0; r < 4; ++r)
                    rmin[it * 4 + r] = fminf(rmin[it * 4 + r],
                        fmaf(-2.f, acc[it][r], x2r[it * 4 + r] + x2j));
        }
    }
    // publish group minima: minb[wave q][row][col cl]
    #pragma unroll
    for (int it = 0; it < 4; ++it)
        #pragma unroll
        for (int r = 0; r < 4; ++r)
            minb[q * 1088 + (it * 16 + qd * 4 + r) * MS + cl] = rmin[it * 4 + r];
    __syncthreads();

    // ====== threshold: 16th-smallest of 128 group minima per row =========
    float dist[KK]; int idx[KK];
    #pragma unroll
    for (int k = 0; k < KK; ++k) { dist[k] = FLT_MAX; idx[k] = 0; }
    #pragma unroll 1
    for (int c = 0; c < 16; ++c)
        insert16(dist, idx, minb[q * 1088 + ln * MS + c], 0);
    __syncthreads();             // minb reads done; X reusable as md

    #pragma unroll 1
    for (int lvl = 0; lvl < 3; ++lvl) {       // 3-level value-only merge
        const int step = 1 << lvl;
        const int m    = (step << 1) - 1;
        const bool pub = (q & m) == step;
        const bool con = (q & m) == 0;
        const int reg  = q >> (lvl + 1);
        if (pub) {
            #pragma unroll
            for (int k = 0; k < KK; ++k)
                md[(reg * 64 + ln) * MS + k] = dist[k];
        }
        __syncthreads();
        if (con) {
            #pragma unroll 1
            for (int k = 0; k < KK; ++k)
                insert16(dist, idx, md[(reg * 64 + ln) * MS + k], 0);
        }
        __syncthreads();
    }
    if (q == 0) ldsthr[ln] = dist[KK - 1] + MARGIN;   // tau = M + margin
    __syncthreads();

    float thrv[16];
    #pragma unroll
    for (int it = 0; it < 4; ++it)
        #pragma unroll
        for (int r = 0; r < 4; ++r)
            thrv[it * 4 + r] = ldsthr[it * 16 + qd * 4 + r];

    // ================= pass 2: re-scan, fill candidate rings ==============
    {
        half8 plo[4], phi[4];
        #pragma unroll
        for (int p = 0; p < 4; ++p) {
            const _Float16* bp = bbase + (size_t)(p * 16) * ND;
            plo[p] = *(const half8*)(bp);
            phi[p] = *(const half8*)(bp + 32);
        }
        #pragma unroll
        for (int jt = 0; jt < NJT; ++jt) {
            const int j0 = jbase + jt * 16;
            half8 blo = plo[jt & 3], bhi = phi[jt & 3];
            {   // prefetch tile jt+4 (clamped)
                const int nt = (jt + 4 < NJT) ? jt + 4 : NJT - 1;
                const _Float16* bp = bbase + (size_t)(nt * 16) * ND;
                plo[jt & 3] = *(const half8*)(bp);
                phi[jt & 3] = *(const half8*)(bp + 32);
            }
            const float x2j = ldsx2[j0 + cl];

            f32x4 acc[4];
            #pragma unroll
            for (int it = 0; it < 4; ++it) {
                acc[it] = __builtin_amdgcn_mfma_f32_16x16x32_f16(
                              afr[it][0], blo, (f32x4){0.f, 0.f, 0.f, 0.f}, 0, 0, 0);
                acc[it] = __builtin_amdgcn_mfma_f32_16x16x32_f16(
                              afr[it][1], bhi, acc[it], 0, 0, 0);
            }
            #pragma unroll
            for (int it = 0; it < 4; ++it) {
                #pragma unroll
                for (int r = 0; r < 4; ++r) {
                    float d2 = fmaf(-2.f, acc[it][r], x2r[it * 4 + r] + x2j);
                    if (d2 < thrv[it * 4 + r]) {
                        int rw = it * 16 + qd * 4 + r;
                        int slot = atomicAdd(&rcnt[rw], 1);
                        if (slot < RCAP) ring[rw * 97 + slot] = j0 + cl;
                    }
                }
            }
        }
    }
    __syncthreads();

    // ========== rescue: exact fp32 recompute of candidates ===============
    const int myrow = rowbase + ln;
    float4 A[16];
    {
        const float4* ra = (const float4*)(hs + (size_t)myrow * ND);
        #pragma unroll
        for (int k = 0; k < 16; ++k) A[k] = ra[k];
    }
    float x2i;   // ascending chain (exact round-1 i-side value)
    {
        float a0 = 0.f, a1 = 0.f, a2 = 0.f, a3 = 0.f;
        #pragma unroll
        for (int k = 0; k < 16; ++k) {
            a0 = fmaf(A[k].x, A[k].x, a0); a1 = fmaf(A[k].y, A[k].y, a1);
            a2 = fmaf(A[k].z, A[k].z, a2); a3 = fmaf(A[k].w, A[k].w, a3);
        }
        x2i = (a0 + a1) + (a2 + a3);
    }
    #pragma unroll
    for (int k = 0; k < KK; ++k) { dist[k] = FLT_MAX; idx[k] = 0; }

    const int cntR = min(rcnt[ln], RCAP);
    int k = q;
    #pragma unroll 1
    for (; k + NW < cntR; k += 2 * NW) {     // 2-way ILP: overlap gathers
        int j0 = ring[ln * 97 + k];
        int j1 = ring[ln * 97 + k + NW];
        const float4* cv0 = (const float4*)(hs + (size_t)j0 * ND);
        const float4* cv1 = (const float4*)(hs + (size_t)j1 * ND);
        float d20 = fmaf(-2.0f, dot64(A, cv0), x2i + ldsx2[j0]);
        float d21 = fmaf(-2.0f, dot64(A, cv1), x2i + ldsx2[j1]);
        insert16x(dist, idx, d20, j0);
        insert16x(dist, idx, d21, j1);
    }
    #pragma unroll 1
    for (; k < cntR; k += NW) {
        int j = ring[ln * 97 + k];
        const float4* cv = (const float4*)(hs + (size_t)j * ND);
        float d2 = fmaf(-2.0f, dot64(A, cv), x2i + ldsx2[j]);
        insert16x(dist, idx, d2, j);
    }
    __syncthreads();             // ring reads done; X reusable as md/mi

    // ---- final exact merge (lex) across the 8 waves ----
    #pragma unroll 1
    for (int lvl = 0; lvl < 3; ++lvl) {
        const int step = 1 << lvl;
        const int m    = (step << 1) - 1;
        const bool pub = (q & m) == step;
        const bool con = (q & m) == 0;
        const int reg  = q >> (lvl + 1);
        if (pub) {
            #pragma unroll
            for (int kk = 0; kk < KK; ++kk) {
                md[(reg * 64 + ln) * MS + kk] = dist[kk];
                mi[(reg * 64 + ln) * MS + kk] = idx[kk];
            }
        }
        __syncthreads();
        if (con) {
            #pragma unroll 1
            for (int kk = 0; kk < KK; ++kk)
                insert16x(dist, idx, md[(reg * 64 + ln) * MS + kk],
                                     mi[(reg * 64 + ln) * MS + kk]);
        }
        __syncthreads();
    }

    // ---- output (wave 0) ----
    if (q == 0) {
        const int off = s * NP;
        const size_t rg = (size_t)off + myrow;
        float* o0 = out + rg * KK;
        float* o1 = out + (size_t)NS * NP * KK + rg * KK;
        float* o2 = out + (size_t)2 * NS * NP * KK + rg * KK;
        #pragma unroll
        for (int kk = 0; kk < KK; ++kk) o0[kk] = dist[kk];
        #pragma unroll
        for (int kk = 0; kk < KK; ++kk) o1[kk] = (float)(idx[kk] + off);
        #pragma unroll
        for (int kk = 0; kk < KK; ++kk) o2[kk] = (float)(off + myrow);
    }
}

extern "C" void kernel_launch(void* const* d_in, const int* in_sizes, int n_in,
                              void* d_out, int out_size, void* d_ws, size_t ws_size,
                              hipStream_t stream)
{
    const float* h = (const float*)d_in[0];
    float* out = (float*)d_out;
    float*    x2 = (float*)d_ws;                     // 32768 floats (128 KB)
    _Float16* hh = (_Float16*)(x2 + NS * NP);        // 16*2048*64 halves (4 MB)

    hipLaunchKernelGGL(prep_kernel, dim3(NS * NP / 64), dim3(64), 0, stream,
                       h, x2, hh);
    hipLaunchKernelGGL(knn_mfma, dim3(NS * 32), dim3(NT), 0, stream,
                       h, hh, x2, out);
}

// Round 12
// 265.690 us; speedup vs baseline: 1.0114x; 1.0112x over previous
//
#include <hip/hip_runtime.h>
#include <hip/hip_fp16.h>
#include <cfloat>

// NearestNeighborGraph: S=16, N=2048, D=64, K=16.
// Round-12 = round-11 algorithm with COALESCED memory access everywhere:
//  - hhT fragment-major f16 layout: B/A-tile fragment loads are contiguous
//    1 KB wave bursts (16 lines) instead of 128-B-stride gathers (64 lines).
//    Rounds 9-11 were bound ~4.5 cyc/CU per lane-touched line (~190 us).
//  - rescue: 4-lane teams load candidate rows coalesced (1 line/team/instr),
//    shuffle-transpose so lane e computes the ORIGINAL chain a_e in exact
//    order; xor-shuffle reduction reproduces (a0+a1)+(a2+a3) bit-exactly.
//  - worklist flatten (prefix scan) so teams stream candidates.
// d2 values bit-identical to rounds 1-11 -> absmax 288 expected.

typedef _Float16 half8 __attribute__((ext_vector_type(8)));
typedef float    f32x4 __attribute__((ext_vector_type(4)));

constexpr int NS = 16, NP = 2048, ND = 64, KK = 16;
constexpr int NW  = 8;              // waves per block
constexpr int NT  = NW * 64;        // 512 threads
constexpr int JW  = NP / NW;        // 256 j per wave
constexpr int NJT = JW / 16;        // 16 j-tiles per wave per pass
constexpr int MS  = 17;             // merge-tree stride
constexpr int RCAP = 64;            // candidate ring slots per row
constexpr int WLCAP = 3072;         // flattened worklist cap
constexpr float MARGIN = 1.0f;

// ---- prep: x2 rotated (j-side) + x2 ascending (i-side) + hhT layout ----
__global__ __launch_bounds__(64)
void prep_kernel(const float* __restrict__ h, float* __restrict__ x2rot,
                 float* __restrict__ x2asc, _Float16* __restrict__ hhT)
{
    int g = blockIdx.x * 64 + threadIdx.x;           // global row
    const float4* row = (const float4*)(h + (size_t)g * ND);
    float4 rv[16];
    #pragma unroll
    for (int k = 0; k < 16; ++k) rv[k] = row[k];

    int ph = g & 15;
    {   // rotated chain (round-1 j-side value)
        float a0 = 0.f, a1 = 0.f, a2 = 0.f, a3 = 0.f;
        #pragma unroll
        for (int k = 0; k < 16; ++k) {
            float4 v = rv[(k + ph) & 15];
            a0 = fmaf(v.x, v.x, a0); a1 = fmaf(v.y, v.y, a1);
            a2 = fmaf(v.z, v.z, a2); a3 = fmaf(v.w, v.w, a3);
        }
        x2rot[g] = (a0 + a1) + (a2 + a3);
    }
    {   // ascending chain (round-1 i-side value)
        float a0 = 0.f, a1 = 0.f, a2 = 0.f, a3 = 0.f;
        #pragma unroll
        for (int k = 0; k < 16; ++k) {
            a0 = fmaf(rv[k].x, rv[k].x, a0); a1 = fmaf(rv[k].y, rv[k].y, a1);
            a2 = fmaf(rv[k].z, rv[k].z, a2); a3 = fmaf(rv[k].w, rv[k].w, a3);
        }
        x2asc[g] = (a0 + a1) + (a2 + a3);
    }
    // fragment-major f16: halves chunk c (8) of row j -> tile*1024 +
    // (c&3)*128 + (j&15)*8 + (c>=4)*512   [so lane ln=qd*16+cl reads ln*8]
    const int s  = g >> 11;
    const int j  = g & 2047;
    _Float16* base = hhT + (size_t)s * NP * ND + (size_t)(j >> 4) * 1024
                         + (j & 15) * 8;
    #pragma unroll
    for (int c = 0; c < 8; ++c) {
        float4 v0 = rv[2 * c], v1 = rv[2 * c + 1];
        half8 p;
        p[0] = (_Float16)v0.x; p[1] = (_Float16)v0.y;
        p[2] = (_Float16)v0.z; p[3] = (_Float16)v0.w;
        p[4] = (_Float16)v1.x; p[5] = (_Float16)v1.y;
        p[6] = (_Float16)v1.z; p[7] = (_Float16)v1.w;
        *(half8*)(base + (c & 3) * 128 + ((c >= 4) ? 512 : 0)) = p;
    }
}

__device__ __forceinline__ void insert16(float (&d)[KK], int (&ix)[KK],
                                         float v, int j)
{
    #pragma unroll
    for (int p = KK - 1; p > 0; --p) {
        bool sh = v < d[p - 1];
        bool he = v < d[p];
        float nd = sh ? d[p - 1] : (he ? v : d[p]);
        int   ni = sh ? ix[p - 1] : (he ? j : ix[p]);
        d[p] = nd; ix[p] = ni;
    }
    if (v < d[0]) { d[0] = v; ix[0] = j; }
}

__device__ __forceinline__ bool lexlt(float a, int ja, float b, int jb)
{
    return (a < b) || (a == b && ja < jb);
}
__device__ __forceinline__ void insert16x(float (&d)[KK], int (&ix)[KK],
                                          float v, int j)
{
    #pragma unroll
    for (int p = KK - 1; p > 0; --p) {
        bool sh = lexlt(v, j, d[p - 1], ix[p - 1]);
        bool he = lexlt(v, j, d[p], ix[p]);
        float nd = sh ? d[p - 1] : (he ? v : d[p]);
        int   ni = sh ? ix[p - 1] : (he ? j : ix[p]);
        d[p] = nd; ix[p] = ni;
    }
    if (lexlt(v, j, d[0], ix[0])) { d[0] = v; ix[0] = j; }
}

__global__ __launch_bounds__(NT)
void knn_mfma(const float* __restrict__ h, const _Float16* __restrict__ hhT,
              const float* __restrict__ x2g, const float* __restrict__ x2a,
              float* __restrict__ out)
{
    // floats: ldsx2[0,2048) xa[2048,2112) thr[2112,2176) rcnt[2176,2240)
    // offs[2240,2305)(ints) A3[2320,6672) X[6672,15376).
    // X time-aliased: minb -> md (thr) -> ring -> wl/wld -> md/mi (final).
    __shared__ __align__(16) float smem[15376];      // 61504 B -> 2 blocks/CU
    float* ldsx2  = smem;
    float* ldsxa  = smem + 2048;
    float* ldsthr = smem + 2112;
    int*   rcnt   = (int*)(smem + 2176);
    int*   offs   = (int*)(smem + 2240);             // [64] + total at [64]
    float* ldsA3  = smem + 2320;                     // 64 rows x 68 (padded)
    float* X      = smem + 6672;                     // 8704 floats
    float* minb   = X;
    float* md     = X;
    int*   mi     = (int*)(X + 4352);
    int*   ring   = (int*)X;                         // 64 x 65 ints
    int*   wl     = (int*)(X + 4160);                // 3072 ints
    float* wld    = X;                               // 3072 floats (ring dead)

    const int t   = threadIdx.x;
    const int ln  = t & 63;
    const int qd  = ln >> 4;
    const int cl  = ln & 15;
    const int q   = t >> 6;
    const int s   = blockIdx.x >> 5;
    const int rb  = blockIdx.x & 31;
    const int rowbase = rb * 64;
    const float*    __restrict__ hs   = h   + (size_t)s * NP * ND;
    const _Float16* __restrict__ hhTs = hhT + (size_t)s * NP * ND;

    // ---- staging: x2 (rot), x2 (asc rows), A3 slices, counters ----
    ((float4*)ldsx2)[t] = ((const float4*)(x2g + s * NP))[t];
    if (t < 64) { ldsxa[t] = x2a[s * NP + rowbase + t]; rcnt[t] = 0; }
    {   // block rows -> component-sliced padded LDS: A3[r*68 + e*16 + k]
        const float* hb = hs + (size_t)rowbase * ND;
        float4 v0 = ((const float4*)hb)[2 * t];
        float4 v1 = ((const float4*)hb)[2 * t + 1];
        #pragma unroll
        for (int u = 0; u < 8; ++u) {
            int f = t * 8 + u;
            int r = f >> 6, d = f & 63, k = d >> 2, e = d & 3;
            float val = (u == 0) ? v0.x : (u == 1) ? v0.y : (u == 2) ? v0.z :
                        (u == 3) ? v0.w : (u == 4) ? v1.x : (u == 5) ? v1.y :
                        (u == 6) ? v1.z : v1.w;
            ldsA3[r * 68 + e * 16 + k] = val;
        }
    }

    // A-frags from hhT (coalesced)
    half8 afr[4][2];
    #pragma unroll
    for (int it = 0; it < 4; ++it) {
        const _Float16* ap = hhTs + (size_t)((rowbase >> 4) + it) * 1024 + ln * 8;
        afr[it][0] = *(const half8*)(ap);
        afr[it][1] = *(const half8*)(ap + 512);
    }
    __syncthreads();

    float x2r[16];
    #pragma unroll
    for (int it = 0; it < 4; ++it)
        #pragma unroll
        for (int r = 0; r < 4; ++r)
            x2r[it * 4 + r] = ldsx2[rowbase + it * 16 + qd * 4 + r];

    const int jbase = q * JW;
    const _Float16* __restrict__ bbT = hhTs + (size_t)(jbase >> 4) * 1024 + ln * 8;

    // ================= pass 1: MFMA scan, group minima only ==============
    float rmin[16];
    #pragma unroll
    for (int k = 0; k < 16; ++k) rmin[k] = FLT_MAX;
    {
        half8 plo[4], phi[4];
        #pragma unroll
        for (int p = 0; p < 4; ++p) {
            plo[p] = *(const half8*)(bbT + (size_t)p * 1024);
            phi[p] = *(const half8*)(bbT + (size_t)p * 1024 + 512);
        }
        #pragma unroll
        for (int jt = 0; jt < NJT; ++jt) {
            const int j0 = jbase + jt * 16;
            half8 blo = plo[jt & 3], bhi = phi[jt & 3];
            {
                const int nt2 = (jt + 4 < NJT) ? jt + 4 : NJT - 1;
                plo[jt & 3] = *(const half8*)(bbT + (size_t)nt2 * 1024);
                phi[jt & 3] = *(const half8*)(bbT + (size_t)nt2 * 1024 + 512);
            }
            const float x2j = ldsx2[j0 + cl];
            f32x4 acc[4];
            #pragma unroll
            for (int it = 0; it < 4; ++it) {
                acc[it] = __builtin_amdgcn_mfma_f32_16x16x32_f16(
                              afr[it][0], blo, (f32x4){0.f, 0.f, 0.f, 0.f}, 0, 0, 0);
                acc[it] = __builtin_amdgcn_mfma_f32_16x16x32_f16(
                              afr[it][1], bhi, acc[it], 0, 0, 0);
            }
            #pragma unroll
            for (int it = 0; it < 4; ++it)
                #pragma unroll
                for (int r = 0; r < 4; ++r)
                    rmin[it * 4 + r] = fminf(rmin[it * 4 + r],
                        fmaf(-2.f, acc[it][r], x2r[it * 4 + r] + x2j));
        }
    }
    #pragma unroll
    for (int it = 0; it < 4; ++it)
        #pragma unroll
        for (int r = 0; r < 4; ++r)
            minb[q * 1088 + (it * 16 + qd * 4 + r) * MS + cl] = rmin[it * 4 + r];
    __syncthreads();

    // ====== threshold: 16th-smallest of 128 group minima per row =========
    float dist[KK]; int idx[KK];
    #pragma unroll
    for (int k = 0; k < KK; ++k) { dist[k] = FLT_MAX; idx[k] = 0; }
    #pragma unroll 1
    for (int c = 0; c < 16; ++c)
        insert16(dist, idx, minb[q * 1088 + ln * MS + c], 0);
    __syncthreads();
    #pragma unroll 1
    for (int lvl = 0; lvl < 3; ++lvl) {
        const int step = 1 << lvl;
        const int m    = (step << 1) - 1;
        const bool pub = (q & m) == step;
        const bool con = (q & m) == 0;
        const int reg  = q >> (lvl + 1);
        if (pub) {
            #pragma unroll
            for (int k = 0; k < KK; ++k)
                md[(reg * 64 + ln) * MS + k] = dist[k];
        }
        __syncthreads();
        if (con) {
            #pragma unroll 1
            for (int k = 0; k < KK; ++k)
                insert16(dist, idx, md[(reg * 64 + ln) * MS + k], 0);
        }
        __syncthreads();
    }
    if (q == 0) ldsthr[ln] = dist[KK - 1] + MARGIN;
    __syncthreads();

    float thrv[16];
    #pragma unroll
    for (int it = 0; it < 4; ++it)
        #pragma unroll
        for (int r = 0; r < 4; ++r)
            thrv[it * 4 + r] = ldsthr[it * 16 + qd * 4 + r];

    // ================= pass 2: re-scan, fill candidate rings ==============
    {
        half8 plo[4], phi[4];
        #pragma unroll
        for (int p = 0; p < 4; ++p) {
            plo[p] = *(const half8*)(bbT + (size_t)p * 1024);
            phi[p] = *(const half8*)(bbT + (size_t)p * 1024 + 512);
        }
        #pragma unroll
        for (int jt = 0; jt < NJT; ++jt) {
            const int j0 = jbase + jt * 16;
            half8 blo = plo[jt & 3], bhi = phi[jt & 3];
            {
                const int nt2 = (jt + 4 < NJT) ? jt + 4 : NJT - 1;
                plo[jt & 3] = *(const half8*)(bbT + (size_t)nt2 * 1024);
                phi[jt & 3] = *(const half8*)(bbT + (size_t)nt2 * 1024 + 512);
            }
            const float x2j = ldsx2[j0 + cl];
            f32x4 acc[4];
            #pragma unroll
            for (int it = 0; it < 4; ++it) {
                acc[it] = __builtin_amdgcn_mfma_f32_16x16x32_f16(
                              afr[it][0], blo, (f32x4){0.f, 0.f, 0.f, 0.f}, 0, 0, 0);
                acc[it] = __builtin_amdgcn_mfma_f32_16x16x32_f16(
                              afr[it][1], bhi, acc[it], 0, 0, 0);
            }
            #pragma unroll
            for (int it = 0; it < 4; ++it) {
                #pragma unroll
                for (int r = 0; r < 4; ++r) {
                    float d2 = fmaf(-2.f, acc[it][r], x2r[it * 4 + r] + x2j);
                    if (d2 < thrv[it * 4 + r]) {
                        int rw = it * 16 + qd * 4 + r;
                        int slot = atomicAdd(&rcnt[rw], 1);
                        if (slot < RCAP) ring[rw * (RCAP + 1) + slot] = j0 + cl;
                    }
                }
            }
        }
    }
    __syncthreads();

    // ---- flatten rings into worklist (prefix scan by wave 0) ----
    if (q == 0) {
        int v = min(rcnt[ln], RCAP);
        int inc = v;
        #pragma unroll
        for (int d = 1; d < 64; d <<= 1) {
            int o = __shfl_up(inc, d, 64);
            if (ln >= d) inc += o;
        }
        offs[ln] = inc - v;
        if (ln == 63) offs[64] = inc;
    }
    __syncthreads();
    {
        int cnt = min(rcnt[ln], RCAP);
        int off = offs[ln];
        for (int k = q; k < cnt; k += NW) {
            int p = off + k;
            if (p < WLCAP) wl[p] = (ln << 11) | ring[ln * (RCAP + 1) + k];
        }
    }
    __syncthreads();
    const int T = min(offs[64], WLCAP);

    // ========== rescue: team-coalesced exact fp32 recompute ==============
    // 4-lane teams: coalesced row load + shuffle 4x4 transpose -> lane e
    // computes the ORIGINAL chain a_e in exact order; xor-reduce matches
    // (a0+a1)+(a2+a3) bitwise.
    {
        const int e = ln & 3;
        for (int w = q * 16 + (ln >> 2); w < T; w += 128) {
            int entry = wl[w];
            int r = entry >> 11, j = entry & 2047;
            const float* jb = hs + (size_t)j * ND + e * 4;
            float a = 0.f;
            #pragma unroll
            for (int c = 0; c < 4; ++c) {
                float4 v = *(const float4*)(jb + c * 16);
                // 4x4 transpose across the team
                float r0 = __shfl_xor(v.x, 1); float r1 = __shfl_xor(v.y, 1);
                float r2 = __shfl_xor(v.z, 1); float r3 = __shfl_xor(v.w, 1);
                bool o1 = (ln & 1);
                float u0 = o1 ? r1 : v.x;
                float u1 = o1 ? v.y : r0;
                float u2 = o1 ? r3 : v.z;
                float u3 = o1 ? v.w : r2;
                float w0 = __shfl_xor(u0, 2); float w1 = __shfl_xor(u1, 2);
                float w2 = __shfl_xor(u2, 2); float w3 = __shfl_xor(u3, 2);
                bool o2 = (ln & 2);
                float f0 = o2 ? w2 : u0;
                float f1 = o2 ? w3 : u1;
                float f2 = o2 ? u2 : w0;
                float f3 = o2 ? u3 : w1;
                f32x4 Ac = *(const f32x4*)(ldsA3 + r * 68 + e * 16 + c * 4);
                a = fmaf(Ac[0], f0, a);
                a = fmaf(Ac[1], f1, a);
                a = fmaf(Ac[2], f2, a);
                a = fmaf(Ac[3], f3, a);
            }
            float s1 = a + __shfl_xor(a, 1);
            float s2 = s1 + __shfl_xor(s1, 2);
            if (e == 0) wld[w] = fmaf(-2.0f, s2, ldsxa[r] + ldsx2[j]);
        }
    }
    __syncthreads();

    // ---- per-row selection from worklist results ----
    #pragma unroll
    for (int k = 0; k < KK; ++k) { dist[k] = FLT_MAX; idx[k] = 0; }
    {
        int cnt = min(rcnt[ln], RCAP);
        int off = offs[ln];
        #pragma unroll 1
        for (int k = q; k < cnt; k += NW) {
            int p = off + k;
            if (p < WLCAP) insert16x(dist, idx, wld[p], wl[p] & 2047);
        }
    }
    __syncthreads();

    // ---- final exact merge (lex) across the 8 waves ----
    #pragma unroll 1
    for (int lvl = 0; lvl < 3; ++lvl) {
        const int step = 1 << lvl;
        const int m    = (step << 1) - 1;
        const bool pub = (q & m) == step;
        const bool con = (q & m) == 0;
        const int reg  = q >> (lvl + 1);
        if (pub) {
            #pragma unroll
            for (int kk = 0; kk < KK; ++kk) {
                md[(reg * 64 + ln) * MS + kk] = dist[kk];
                mi[(reg * 64 + ln) * MS + kk] = idx[kk];
            }
        }
        __syncthreads();
        if (con) {
            #pragma unroll 1
            for (int kk = 0; kk < KK; ++kk)
                insert16x(dist, idx, md[(reg * 64 + ln) * MS + kk],
                                     mi[(reg * 64 + ln) * MS + kk]);
        }
        __syncthreads();
    }

    // ---- output (wave 0) ----
    if (q == 0) {
        const int off = s * NP;
        const int myrow = rowbase + ln;
        const size_t rg = (size_t)off + myrow;
        float* o0 = out + rg * KK;
        float* o1 = out + (size_t)NS * NP * KK + rg * KK;
        float* o2 = out + (size_t)2 * NS * NP * KK + rg * KK;
        #pragma unroll
        for (int kk = 0; kk < KK; ++kk) o0[kk] = dist[kk];
        #pragma unroll
        for (int kk = 0; kk < KK; ++kk) o1[kk] = (float)(idx[kk] + off);
        #pragma unroll
        for (int kk = 0; kk < KK; ++kk) o2[kk] = (float)(off + myrow);
    }
}

extern "C" void kernel_launch(void* const* d_in, const int* in_sizes, int n_in,
                              void* d_out, int out_size, void* d_ws, size_t ws_size,
                              hipStream_t stream)
{
    const float* h = (const float*)d_in[0];
    float* out = (float*)d_out;
    float*    x2rot = (float*)d_ws;                  // 32768 floats
    float*    x2asc = x2rot + NS * NP;               // 32768 floats
    _Float16* hhT   = (_Float16*)(x2asc + NS * NP);  // 2M halves (4 MB)

    hipLaunchKernelGGL(prep_kernel, dim3(NS * NP / 64), dim3(64), 0, stream,
                       h, x2rot, x2asc, hhT);
    hipLaunchKernelGGL(knn_mfma, dim3(NS * 32), dim3(NT), 0, stream,
                       h, hhT, x2rot, x2asc, out);
}